// Round 10
// baseline (158.922 us; speedup 1.0000x reference)
//
#include <hip/hip_runtime.h>
#include <hip/hip_bf16.h>
#include <math.h>

// B=4, L=2048, D_MODEL=512, H=8, d_head=64, fp32 in/out.
// Round 10: ONE change vs r9 — attn XCD-locality swizzle.
//   Old: bh = blockIdx & 31  -> every XCD touches all 32 heads (16 MB >> 4 MB L2),
//        536 MB of K/V fragment re-reads served by L3 (~10 TB/s) ~= 54 us wall.
//   New: bh = (blockIdx&7)*4 + ((blockIdx>>3)&3), qt = blockIdx>>5
//        -> each XCD owns 4 heads (2 MB working set, L2-resident).

#define MDIM 8192
#define DMODEL 512
#define NHEAD 8
#define DHEAD 64
#define LSEQ 2048

typedef __attribute__((ext_vector_type(8))) short short8;
typedef __attribute__((ext_vector_type(4))) float floatx4;

struct alignas(16) bf16x8 { __hip_bfloat16 v[8]; };
struct alignas(8)  bf16x4 { __hip_bfloat16 v[4]; };

__device__ __forceinline__ void load_lds16(const __hip_bfloat16* g, __hip_bfloat16* l) {
    __builtin_amdgcn_global_load_lds(
        (const __attribute__((address_space(1))) void*)g,
        (__attribute__((address_space(3))) void*)l,
        16, 0, 0);
}

__device__ __forceinline__ float fast_exp2(float x) {
#if __has_builtin(__builtin_amdgcn_exp2f)
    return __builtin_amdgcn_exp2f(x);
#else
    return __expf(x * 0.69314718055994531f);
#endif
}

// ---------------- prologue casts ----------------
__global__ __launch_bounds__(256) void cast_x_kernel(
    const float* __restrict__ x, __hip_bfloat16* __restrict__ xb)
{
    size_t i = ((size_t)blockIdx.x * 256 + threadIdx.x) * 8;
    float4 a = *reinterpret_cast<const float4*>(x + i);
    float4 b = *reinterpret_cast<const float4*>(x + i + 4);
    bf16x8 o;
    o.v[0] = __float2bfloat16(a.x); o.v[1] = __float2bfloat16(a.y);
    o.v[2] = __float2bfloat16(a.z); o.v[3] = __float2bfloat16(a.w);
    o.v[4] = __float2bfloat16(b.x); o.v[5] = __float2bfloat16(b.y);
    o.v[6] = __float2bfloat16(b.z); o.v[7] = __float2bfloat16(b.w);
    *reinterpret_cast<bf16x8*>(xb + i) = o;
}

__global__ __launch_bounds__(256) void transpose_cast_w(
    const float* __restrict__ Wq, const float* __restrict__ Wk,
    const float* __restrict__ Wv, const float* __restrict__ Wo,
    __hip_bfloat16* __restrict__ Wt)
{
    __shared__ float t[32][33];
    const int z = blockIdx.z;
    const float* W = z == 0 ? Wq : (z == 1 ? Wk : (z == 2 ? Wv : Wo));
    __hip_bfloat16* dst = Wt + ((size_t)z << 18);
    int k0 = blockIdx.x * 32, n0 = blockIdx.y * 32;
    int c = threadIdx.x & 31, r = threadIdx.x >> 5;
    #pragma unroll
    for (int i = 0; i < 4; ++i)
        t[r + 8 * i][c] = W[(size_t)(k0 + r + 8 * i) * DMODEL + n0 + c];
    __syncthreads();
    #pragma unroll
    for (int i = 0; i < 4; ++i)
        dst[(size_t)(n0 + r + 8 * i) * DMODEL + k0 + c] = __float2bfloat16(t[c][r + 8 * i]);
}

// ---------------- QKV projection: bf16 MFMA 128x128, frag-major epilogues -------
__global__ __launch_bounds__(256) void gemm_qkv_mfma(
    const __hip_bfloat16* __restrict__ xb,
    const __hip_bfloat16* __restrict__ Wt,
    const float* __restrict__ bq, const float* __restrict__ bk,
    const float* __restrict__ bv,
    __hip_bfloat16* __restrict__ Q2, __hip_bfloat16* __restrict__ K2,
    __hip_bfloat16* __restrict__ V2)
{
    __shared__ __hip_bfloat16 As[128 * 64];
    __shared__ __hip_bfloat16 Bs[128 * 64];

    const int tid = threadIdx.x;
    const int wid = tid >> 6, lane = tid & 63;
    const int l16 = lane & 15, quad = lane >> 4;
    const int wr = wid >> 1, wc = wid & 1;
    const int row0 = blockIdx.x * 128;
    const int which = blockIdx.y >> 2;
    const int col0 = (blockIdx.y & 3) * 128;
    const __hip_bfloat16* Wb = Wt + ((size_t)which << 18);
    const float* bias = which == 0 ? bq : (which == 1 ? bk : bv);

    const int r8 = lane >> 3, slot = lane & 7;
    const int cchunk = slot ^ (r8 & 7);

    floatx4 acc[4][4];
    #pragma unroll
    for (int i = 0; i < 4; ++i)
        #pragma unroll
        for (int j = 0; j < 4; ++j) acc[i][j] = floatx4{0.f, 0.f, 0.f, 0.f};

    for (int kt = 0; kt < DMODEL / 64; ++kt) {
        __syncthreads();
        #pragma unroll
        for (int j = 0; j < 4; ++j) {
            int seg = wid * 4 + j;
            int m = seg * 8 + r8;
            load_lds16(xb + (size_t)(row0 + m) * DMODEL + kt * 64 + cchunk * 8,
                       As + seg * 512);
            load_lds16(Wb + (size_t)(col0 + m) * DMODEL + kt * 64 + cchunk * 8,
                       Bs + seg * 512);
        }
        __syncthreads();

        #pragma unroll
        for (int ks = 0; ks < 2; ++ks) {
            const int c = ks * 4 + quad;
            short8 af[4], bf[4];
            #pragma unroll
            for (int mt = 0; mt < 4; ++mt) {
                int m = wr * 64 + mt * 16 + l16;
                af[mt] = *reinterpret_cast<const short8*>(As + m * 64 + ((c ^ (m & 7)) << 3));
            }
            #pragma unroll
            for (int nt = 0; nt < 4; ++nt) {
                int n = wc * 64 + nt * 16 + l16;
                bf[nt] = *reinterpret_cast<const short8*>(Bs + n * 64 + ((c ^ (n & 7)) << 3));
            }
            if (which < 2) {
                #pragma unroll
                for (int mt = 0; mt < 4; ++mt)
                    #pragma unroll
                    for (int nt = 0; nt < 4; ++nt)
                        acc[mt][nt] = __builtin_amdgcn_mfma_f32_16x16x32_bf16(
                            bf[nt], af[mt], acc[mt][nt], 0, 0, 0);
            } else {
                #pragma unroll
                for (int mt = 0; mt < 4; ++mt)
                    #pragma unroll
                    for (int nt = 0; nt < 4; ++nt)
                        acc[mt][nt] = __builtin_amdgcn_mfma_f32_16x16x32_bf16(
                            af[mt], bf[nt], acc[mt][nt], 0, 0, 0);
            }
        }
    }

    const float QSCALE = 0.18033688011112042f;   // (1/8) * log2(e)

    if (which < 2) {
        __hip_bfloat16* dst = (which == 0) ? Q2 : K2;
        const float sc = (which == 0) ? QSCALE : 1.0f;
        #pragma unroll
        for (int mt = 0; mt < 4; ++mt) {
            const int mm = row0 + wr * 64 + mt * 16 + l16;   // x row (q or key)
            const int b = mm >> 11, l = mm & 2047;
            int rowi;
            if (which == 0) {
                rowi = l;
            } else {
                int hi = l & ~127, w7 = l & 127;
                rowi = hi | (w7 & 96) | (((w7 >> 3) & 3) << 2)
                          | (((w7 >> 2) & 1) << 4) | (w7 & 3);
            }
            #pragma unroll
            for (int nt = 0; nt < 4; ++nt) {
                const int nnb = col0 + wc * 64 + nt * 16 + quad * 4;
                const float4 bv4 = *reinterpret_cast<const float4*>(&bias[nnb]);
                const int h = nnb >> 6, d = nnb & 63;
                const int s = d >> 5, q4 = (d >> 3) & 3, jb = d & 7;
                bf16x4 pk;
                pk.v[0] = __float2bfloat16((acc[mt][nt][0] + bv4.x) * sc);
                pk.v[1] = __float2bfloat16((acc[mt][nt][1] + bv4.y) * sc);
                pk.v[2] = __float2bfloat16((acc[mt][nt][2] + bv4.z) * sc);
                pk.v[3] = __float2bfloat16((acc[mt][nt][3] + bv4.w) * sc);
                size_t idx = ((((size_t)(b * NHEAD + h) * 128 + (rowi >> 4)) * 2 + s) << 9)
                             + q4 * 128 + (rowi & 15) * 8 + jb;
                *reinterpret_cast<bf16x4*>(dst + idx) = pk;
            }
        }
    } else {
        #pragma unroll
        for (int mt = 0; mt < 4; ++mt) {
            const int mmb = row0 + wr * 64 + mt * 16 + quad * 4;
            const int b = mmb >> 11, lb = mmb & 2047;
            #pragma unroll
            for (int nt = 0; nt < 4; ++nt) {
                const int nn = col0 + wc * 64 + nt * 16 + l16;
                const int h = nn >> 6, d = nn & 63;
                const float bv = bias[nn];
                bf16x4 pk;
                pk.v[0] = __float2bfloat16(acc[mt][nt][0] + bv);
                pk.v[1] = __float2bfloat16(acc[mt][nt][1] + bv);
                pk.v[2] = __float2bfloat16(acc[mt][nt][2] + bv);
                pk.v[3] = __float2bfloat16(acc[mt][nt][3] + bv);
                size_t idx = ((((size_t)(b * NHEAD + h) * 64 + (lb >> 5)) * 4 + (d >> 4)) << 9)
                             + ((lb >> 3) & 3) * 128 + (d & 15) * 8 + (lb & 7);
                *reinterpret_cast<bf16x4*>(V2 + idx) = pk;
            }
        }
    }
}

// ---------------- output projection: bf16 MFMA, 128x64 tile (512 blocks) --------
__global__ __launch_bounds__(256) void gemm_out_mfma(
    const __hip_bfloat16* __restrict__ Zb,
    const __hip_bfloat16* __restrict__ WoT,
    const float* __restrict__ bo, float* __restrict__ out)
{
    __shared__ __hip_bfloat16 As[128 * 64];
    __shared__ __hip_bfloat16 Bs[64 * 64];

    const int tid = threadIdx.x;
    const int wid = tid >> 6, lane = tid & 63;
    const int l16 = lane & 15, quad = lane >> 4;
    const int row0 = blockIdx.x * 128;
    const int col0 = blockIdx.y * 64;
    const int r8 = lane >> 3, slot = lane & 7;
    const int cchunk = slot ^ (r8 & 7);

    floatx4 acc[2][4];
    #pragma unroll
    for (int i = 0; i < 2; ++i)
        #pragma unroll
        for (int j = 0; j < 4; ++j) acc[i][j] = floatx4{0.f, 0.f, 0.f, 0.f};

    for (int kt = 0; kt < DMODEL / 64; ++kt) {
        __syncthreads();
        #pragma unroll
        for (int j = 0; j < 4; ++j) {
            int seg = wid * 4 + j;
            int m = seg * 8 + r8;
            load_lds16(Zb + (size_t)(row0 + m) * DMODEL + kt * 64 + cchunk * 8,
                       As + seg * 512);
        }
        #pragma unroll
        for (int j = 0; j < 2; ++j) {
            int seg = wid * 2 + j;
            int n = seg * 8 + r8;
            load_lds16(WoT + (size_t)(col0 + n) * DMODEL + kt * 64 + cchunk * 8,
                       Bs + seg * 512);
        }
        __syncthreads();

        #pragma unroll
        for (int ks = 0; ks < 2; ++ks) {
            const int c = ks * 4 + quad;
            short8 af[2], bf[4];
            #pragma unroll
            for (int mt = 0; mt < 2; ++mt) {
                int m = wid * 32 + mt * 16 + l16;
                af[mt] = *reinterpret_cast<const short8*>(As + m * 64 + ((c ^ (m & 7)) << 3));
            }
            #pragma unroll
            for (int nt = 0; nt < 4; ++nt) {
                int n = nt * 16 + l16;
                bf[nt] = *reinterpret_cast<const short8*>(Bs + n * 64 + ((c ^ (n & 7)) << 3));
            }
            #pragma unroll
            for (int mt = 0; mt < 2; ++mt)
                #pragma unroll
                for (int nt = 0; nt < 4; ++nt)
                    acc[mt][nt] = __builtin_amdgcn_mfma_f32_16x16x32_bf16(
                        af[mt], bf[nt], acc[mt][nt], 0, 0, 0);
        }
    }

    #pragma unroll
    for (int mt = 0; mt < 2; ++mt) {
        const int mmbase = row0 + wid * 32 + mt * 16 + quad * 4;
        #pragma unroll
        for (int nt = 0; nt < 4; ++nt) {
            const int nn = col0 + nt * 16 + l16;
            const float bias_v = bo[nn];
            #pragma unroll
            for (int r = 0; r < 4; ++r)
                out[(size_t)(mmbase + r) * DMODEL + nn] = acc[mt][nt][r] + bias_v;
        }
    }
}

// ---------------- flash attention: zero-LDS main loop, XCD-local heads ----------
__global__ __launch_bounds__(256) void attn_mfma(
    const __hip_bfloat16* __restrict__ Q2,
    const __hip_bfloat16* __restrict__ K2,
    const __hip_bfloat16* __restrict__ V2,
    __hip_bfloat16* __restrict__ Z)         // [B,L,512] bf16
{
    __shared__ float smem[4608];            // Lred [256] + Ored [4352] (stride 68)
    float* Lred = smem;
    float* Ored = smem + 256;

    // XCD-locality: block i -> XCD (i&7). Give each XCD 4 heads (2 MB K/V, L2-fit).
    const int bh = (blockIdx.x & 7) * 4 + ((blockIdx.x >> 3) & 3);
    const int qt = blockIdx.x >> 5;
    const int q0 = qt * 64;
    const int tid = threadIdx.x;
    const int wid = tid >> 6, lane = tid & 63;
    const int l16 = lane & 15, quad = lane >> 4;

    const __hip_bfloat16* Kc = K2 + (((size_t)bh * 128 * 2) << 9);
    const __hip_bfloat16* Vc = V2 + (((size_t)bh * 64 * 4) << 9);

    short8 qb[4][2];
    #pragma unroll
    for (int nt = 0; nt < 4; ++nt)
        #pragma unroll
        for (int s = 0; s < 2; ++s)
            qb[nt][s] = *reinterpret_cast<const short8*>(
                Q2 + ((((size_t)bh * 128 + qt * 4 + nt) * 2 + s) << 9) + lane * 8);

    floatx4 acc[4][4];
    #pragma unroll
    for (int i = 0; i < 4; ++i)
        #pragma unroll
        for (int j = 0; j < 4; ++j) acc[i][j] = floatx4{0.f, 0.f, 0.f, 0.f};
    floatx4 accl[4];
    #pragma unroll
    for (int i = 0; i < 4; ++i) accl[i] = floatx4{0.f, 0.f, 0.f, 0.f};

    union { short8 s8; __hip_bfloat16 h[8]; } onesu;
    #pragma unroll
    for (int i = 0; i < 8; ++i) onesu.h[i] = __float2bfloat16(1.0f);
    const short8 ones = onesu.s8;

    const floatx4 fzero = floatx4{0.f, 0.f, 0.f, 0.f};

    const __hip_bfloat16* kp = Kc + (((size_t)wid * 4) << 9) + lane * 8;
    const __hip_bfloat16* vp = Vc + (((size_t)wid * 4) << 9) + lane * 8;

    for (int kt = 0; kt < LSEQ / 128; ++kt) {
        short8 kb[2][2], vb[4];
        #pragma unroll
        for (int t = 0; t < 2; ++t)
            #pragma unroll
            for (int s = 0; s < 2; ++s)
                kb[t][s] = *reinterpret_cast<const short8*>(kp + ((t * 2 + s) << 9));
        #pragma unroll
        for (int dt = 0; dt < 4; ++dt)
            vb[dt] = *reinterpret_cast<const short8*>(vp + (dt << 9));
        kp += (size_t)16 << 9;
        vp += (size_t)16 << 9;

        floatx4 sacc[2][4];
        #pragma unroll
        for (int nt = 0; nt < 4; ++nt) {
            sacc[0][nt] = __builtin_amdgcn_mfma_f32_16x16x32_bf16(
                kb[0][0], qb[nt][0], fzero, 0, 0, 0);
            sacc[1][nt] = __builtin_amdgcn_mfma_f32_16x16x32_bf16(
                kb[1][0], qb[nt][0], fzero, 0, 0, 0);
        }
        #pragma unroll
        for (int nt = 0; nt < 4; ++nt) {
            sacc[0][nt] = __builtin_amdgcn_mfma_f32_16x16x32_bf16(
                kb[0][1], qb[nt][1], sacc[0][nt], 0, 0, 0);
            sacc[1][nt] = __builtin_amdgcn_mfma_f32_16x16x32_bf16(
                kb[1][1], qb[nt][1], sacc[1][nt], 0, 0, 0);
        }

        short8 pa[4];
        #pragma unroll
        for (int nt = 0; nt < 4; ++nt) {
            union { short8 s8; __hip_bfloat16 h[8]; } u;
            #pragma unroll
            for (int t = 0; t < 2; ++t)
                #pragma unroll
                for (int r = 0; r < 4; ++r)
                    u.h[t * 4 + r] = __float2bfloat16(fast_exp2(sacc[t][nt][r]));
            pa[nt] = u.s8;
        }

        #pragma unroll
        for (int nt = 0; nt < 4; ++nt)
            accl[nt] = __builtin_amdgcn_mfma_f32_16x16x32_bf16(
                pa[nt], ones, accl[nt], 0, 0, 0);

        #pragma unroll
        for (int dt = 0; dt < 4; ++dt)
            #pragma unroll
            for (int nt = 0; nt < 4; ++nt)
                acc[nt][dt] = __builtin_amdgcn_mfma_f32_16x16x32_bf16(
                    pa[nt], vb[dt], acc[nt][dt], 0, 0, 0);
    }

    // -------- epilogue: cross-wave reduction of lsum and O --------
    if (l16 == 0) {
        #pragma unroll
        for (int nt = 0; nt < 4; ++nt)
            #pragma unroll
            for (int r = 0; r < 4; ++r)
                Lred[wid * 64 + nt * 16 + quad * 4 + r] = accl[nt][r];
    }

    const int b = bh >> 3, h = bh & 7;
    const int ql = tid >> 2;
    const int dg = tid & 3;
    float inv = 0.f;

    for (int dt = 0; dt < 4; ++dt) {
        __syncthreads();
        #pragma unroll
        for (int nt = 0; nt < 4; ++nt)
            *reinterpret_cast<floatx4*>(
                &Ored[(wid * 16 + l16) * 68 + nt * 16 + quad * 4]) = acc[nt][dt];
        __syncthreads();

        if (dt == 0)
            inv = 1.f / (Lred[ql] + Lred[64 + ql] + Lred[128 + ql] + Lred[192 + ql]);

        bf16x4 zo;
        #pragma unroll
        for (int i = 0; i < 4; ++i) {
            int d = dg * 4 + i;
            float ssum = Ored[d * 68 + ql] + Ored[(16 + d) * 68 + ql]
                       + Ored[(32 + d) * 68 + ql] + Ored[(48 + d) * 68 + ql];
            zo.v[i] = __float2bfloat16(ssum * inv);
        }
        *reinterpret_cast<bf16x4*>(
            Z + (size_t)(b * LSEQ + q0 + ql) * DMODEL + h * 64 + dt * 16 + dg * 4) = zo;
    }
}

extern "C" void kernel_launch(void* const* d_in, const int* in_sizes, int n_in,
                              void* d_out, int out_size, void* d_ws, size_t ws_size,
                              hipStream_t stream)
{
    const float* x  = (const float*)d_in[0];
    const float* Wq = (const float*)d_in[1]; const float* bq = (const float*)d_in[2];
    const float* Wk = (const float*)d_in[3]; const float* bk = (const float*)d_in[4];
    const float* Wv = (const float*)d_in[5]; const float* bv = (const float*)d_in[6];
    const float* Wo = (const float*)d_in[7]; const float* bo = (const float*)d_in[8];
    float* out = (float*)d_out;

    const size_t nqkv = (size_t)MDIM * DMODEL;
    __hip_bfloat16* xb = (__hip_bfloat16*)d_ws;
    __hip_bfloat16* Wt = xb + nqkv;
    __hip_bfloat16* Q2 = Wt + ((size_t)4 << 18);
    __hip_bfloat16* K2 = Q2 + nqkv;
    __hip_bfloat16* V2 = K2 + nqkv;
    __hip_bfloat16* Zb = V2 + nqkv;

    cast_x_kernel<<<dim3(MDIM * DMODEL / (256 * 8)), 256, 0, stream>>>(x, xb);
    transpose_cast_w<<<dim3(16, 16, 4), 256, 0, stream>>>(Wq, Wk, Wv, Wo, Wt);

    gemm_qkv_mfma<<<dim3(MDIM / 128, 12), 256, 0, stream>>>(
        xb, Wt, bq, bk, bv, Q2, K2, V2);

    attn_mfma<<<dim3(32 * (LSEQ / 64)), 256, 0, stream>>>(Q2, K2, V2, Zb);

    gemm_out_mfma<<<dim3(MDIM / 128, DMODEL / 64), 256, 0, stream>>>(
        Zb, Wt + ((size_t)3 << 18), bo, out);
}

// Round 11
// 157.977 us; speedup vs baseline: 1.0060x; 1.0060x over previous
//
#include <hip/hip_runtime.h>
#include <hip/hip_bf16.h>
#include <math.h>

// B=4, L=2048, D_MODEL=512, H=8, d_head=64, fp32 in/out.
// Round 11: attn software pipeline — iter k: loads(k+1) -> exp/cvt(sacc_k) [VALU]
// -> S_{k+1} [MFMA, indep of exp] -> PV_k [MFMA]. The 32-MFMA burst has no
// same-wave VALU dependency, so the 2 resident waves/SIMD anti-phase and fill
// both pipes (r10 showed MFMA 30% + VALU 30% serialized = the 51 us wall).
// lsum back to VALU tree adds (drops 4 MFMA/iter + 16 AGPR).

#define MDIM 8192
#define DMODEL 512
#define NHEAD 8
#define DHEAD 64
#define LSEQ 2048

typedef __attribute__((ext_vector_type(8))) short short8;
typedef __attribute__((ext_vector_type(4))) float floatx4;

struct alignas(16) bf16x8 { __hip_bfloat16 v[8]; };
struct alignas(8)  bf16x4 { __hip_bfloat16 v[4]; };

__device__ __forceinline__ void load_lds16(const __hip_bfloat16* g, __hip_bfloat16* l) {
    __builtin_amdgcn_global_load_lds(
        (const __attribute__((address_space(1))) void*)g,
        (__attribute__((address_space(3))) void*)l,
        16, 0, 0);
}

__device__ __forceinline__ float fast_exp2(float x) {
#if __has_builtin(__builtin_amdgcn_exp2f)
    return __builtin_amdgcn_exp2f(x);
#else
    return __expf(x * 0.69314718055994531f);
#endif
}

// ---------------- prologue casts ----------------
__global__ __launch_bounds__(256) void cast_x_kernel(
    const float* __restrict__ x, __hip_bfloat16* __restrict__ xb)
{
    size_t i = ((size_t)blockIdx.x * 256 + threadIdx.x) * 8;
    float4 a = *reinterpret_cast<const float4*>(x + i);
    float4 b = *reinterpret_cast<const float4*>(x + i + 4);
    bf16x8 o;
    o.v[0] = __float2bfloat16(a.x); o.v[1] = __float2bfloat16(a.y);
    o.v[2] = __float2bfloat16(a.z); o.v[3] = __float2bfloat16(a.w);
    o.v[4] = __float2bfloat16(b.x); o.v[5] = __float2bfloat16(b.y);
    o.v[6] = __float2bfloat16(b.z); o.v[7] = __float2bfloat16(b.w);
    *reinterpret_cast<bf16x8*>(xb + i) = o;
}

__global__ __launch_bounds__(256) void transpose_cast_w(
    const float* __restrict__ Wq, const float* __restrict__ Wk,
    const float* __restrict__ Wv, const float* __restrict__ Wo,
    __hip_bfloat16* __restrict__ Wt)
{
    __shared__ float t[32][33];
    const int z = blockIdx.z;
    const float* W = z == 0 ? Wq : (z == 1 ? Wk : (z == 2 ? Wv : Wo));
    __hip_bfloat16* dst = Wt + ((size_t)z << 18);
    int k0 = blockIdx.x * 32, n0 = blockIdx.y * 32;
    int c = threadIdx.x & 31, r = threadIdx.x >> 5;
    #pragma unroll
    for (int i = 0; i < 4; ++i)
        t[r + 8 * i][c] = W[(size_t)(k0 + r + 8 * i) * DMODEL + n0 + c];
    __syncthreads();
    #pragma unroll
    for (int i = 0; i < 4; ++i)
        dst[(size_t)(n0 + r + 8 * i) * DMODEL + k0 + c] = __float2bfloat16(t[c][r + 8 * i]);
}

// ---------------- QKV projection: bf16 MFMA 128x128, frag-major epilogues -------
__global__ __launch_bounds__(256) void gemm_qkv_mfma(
    const __hip_bfloat16* __restrict__ xb,
    const __hip_bfloat16* __restrict__ Wt,
    const float* __restrict__ bq, const float* __restrict__ bk,
    const float* __restrict__ bv,
    __hip_bfloat16* __restrict__ Q2, __hip_bfloat16* __restrict__ K2,
    __hip_bfloat16* __restrict__ V2)
{
    __shared__ __hip_bfloat16 As[128 * 64];
    __shared__ __hip_bfloat16 Bs[128 * 64];

    const int tid = threadIdx.x;
    const int wid = tid >> 6, lane = tid & 63;
    const int l16 = lane & 15, quad = lane >> 4;
    const int wr = wid >> 1, wc = wid & 1;
    const int row0 = blockIdx.x * 128;
    const int which = blockIdx.y >> 2;
    const int col0 = (blockIdx.y & 3) * 128;
    const __hip_bfloat16* Wb = Wt + ((size_t)which << 18);
    const float* bias = which == 0 ? bq : (which == 1 ? bk : bv);

    const int r8 = lane >> 3, slot = lane & 7;
    const int cchunk = slot ^ (r8 & 7);

    floatx4 acc[4][4];
    #pragma unroll
    for (int i = 0; i < 4; ++i)
        #pragma unroll
        for (int j = 0; j < 4; ++j) acc[i][j] = floatx4{0.f, 0.f, 0.f, 0.f};

    for (int kt = 0; kt < DMODEL / 64; ++kt) {
        __syncthreads();
        #pragma unroll
        for (int j = 0; j < 4; ++j) {
            int seg = wid * 4 + j;
            int m = seg * 8 + r8;
            load_lds16(xb + (size_t)(row0 + m) * DMODEL + kt * 64 + cchunk * 8,
                       As + seg * 512);
            load_lds16(Wb + (size_t)(col0 + m) * DMODEL + kt * 64 + cchunk * 8,
                       Bs + seg * 512);
        }
        __syncthreads();

        #pragma unroll
        for (int ks = 0; ks < 2; ++ks) {
            const int c = ks * 4 + quad;
            short8 af[4], bf[4];
            #pragma unroll
            for (int mt = 0; mt < 4; ++mt) {
                int m = wr * 64 + mt * 16 + l16;
                af[mt] = *reinterpret_cast<const short8*>(As + m * 64 + ((c ^ (m & 7)) << 3));
            }
            #pragma unroll
            for (int nt = 0; nt < 4; ++nt) {
                int n = wc * 64 + nt * 16 + l16;
                bf[nt] = *reinterpret_cast<const short8*>(Bs + n * 64 + ((c ^ (n & 7)) << 3));
            }
            if (which < 2) {
                #pragma unroll
                for (int mt = 0; mt < 4; ++mt)
                    #pragma unroll
                    for (int nt = 0; nt < 4; ++nt)
                        acc[mt][nt] = __builtin_amdgcn_mfma_f32_16x16x32_bf16(
                            bf[nt], af[mt], acc[mt][nt], 0, 0, 0);
            } else {
                #pragma unroll
                for (int mt = 0; mt < 4; ++mt)
                    #pragma unroll
                    for (int nt = 0; nt < 4; ++nt)
                        acc[mt][nt] = __builtin_amdgcn_mfma_f32_16x16x32_bf16(
                            af[mt], bf[nt], acc[mt][nt], 0, 0, 0);
            }
        }
    }

    const float QSCALE = 0.18033688011112042f;   // (1/8) * log2(e)

    if (which < 2) {
        __hip_bfloat16* dst = (which == 0) ? Q2 : K2;
        const float sc = (which == 0) ? QSCALE : 1.0f;
        #pragma unroll
        for (int mt = 0; mt < 4; ++mt) {
            const int mm = row0 + wr * 64 + mt * 16 + l16;   // x row (q or key)
            const int b = mm >> 11, l = mm & 2047;
            int rowi;
            if (which == 0) {
                rowi = l;
            } else {
                int hi = l & ~127, w7 = l & 127;
                rowi = hi | (w7 & 96) | (((w7 >> 3) & 3) << 2)
                          | (((w7 >> 2) & 1) << 4) | (w7 & 3);
            }
            #pragma unroll
            for (int nt = 0; nt < 4; ++nt) {
                const int nnb = col0 + wc * 64 + nt * 16 + quad * 4;
                const float4 bv4 = *reinterpret_cast<const float4*>(&bias[nnb]);
                const int h = nnb >> 6, d = nnb & 63;
                const int s = d >> 5, q4 = (d >> 3) & 3, jb = d & 7;
                bf16x4 pk;
                pk.v[0] = __float2bfloat16((acc[mt][nt][0] + bv4.x) * sc);
                pk.v[1] = __float2bfloat16((acc[mt][nt][1] + bv4.y) * sc);
                pk.v[2] = __float2bfloat16((acc[mt][nt][2] + bv4.z) * sc);
                pk.v[3] = __float2bfloat16((acc[mt][nt][3] + bv4.w) * sc);
                size_t idx = ((((size_t)(b * NHEAD + h) * 128 + (rowi >> 4)) * 2 + s) << 9)
                             + q4 * 128 + (rowi & 15) * 8 + jb;
                *reinterpret_cast<bf16x4*>(dst + idx) = pk;
            }
        }
    } else {
        #pragma unroll
        for (int mt = 0; mt < 4; ++mt) {
            const int mmb = row0 + wr * 64 + mt * 16 + quad * 4;
            const int b = mmb >> 11, lb = mmb & 2047;
            #pragma unroll
            for (int nt = 0; nt < 4; ++nt) {
                const int nn = col0 + wc * 64 + nt * 16 + l16;
                const int h = nn >> 6, d = nn & 63;
                const float bv = bias[nn];
                bf16x4 pk;
                pk.v[0] = __float2bfloat16(acc[mt][nt][0] + bv);
                pk.v[1] = __float2bfloat16(acc[mt][nt][1] + bv);
                pk.v[2] = __float2bfloat16(acc[mt][nt][2] + bv);
                pk.v[3] = __float2bfloat16(acc[mt][nt][3] + bv);
                size_t idx = ((((size_t)(b * NHEAD + h) * 64 + (lb >> 5)) * 4 + (d >> 4)) << 9)
                             + ((lb >> 3) & 3) * 128 + (d & 15) * 8 + (lb & 7);
                *reinterpret_cast<bf16x4*>(V2 + idx) = pk;
            }
        }
    }
}

// ---------------- output projection: bf16 MFMA, 128x64 tile (512 blocks) --------
__global__ __launch_bounds__(256) void gemm_out_mfma(
    const __hip_bfloat16* __restrict__ Zb,
    const __hip_bfloat16* __restrict__ WoT,
    const float* __restrict__ bo, float* __restrict__ out)
{
    __shared__ __hip_bfloat16 As[128 * 64];
    __shared__ __hip_bfloat16 Bs[64 * 64];

    const int tid = threadIdx.x;
    const int wid = tid >> 6, lane = tid & 63;
    const int l16 = lane & 15, quad = lane >> 4;
    const int row0 = blockIdx.x * 128;
    const int col0 = blockIdx.y * 64;
    const int r8 = lane >> 3, slot = lane & 7;
    const int cchunk = slot ^ (r8 & 7);

    floatx4 acc[2][4];
    #pragma unroll
    for (int i = 0; i < 2; ++i)
        #pragma unroll
        for (int j = 0; j < 4; ++j) acc[i][j] = floatx4{0.f, 0.f, 0.f, 0.f};

    for (int kt = 0; kt < DMODEL / 64; ++kt) {
        __syncthreads();
        #pragma unroll
        for (int j = 0; j < 4; ++j) {
            int seg = wid * 4 + j;
            int m = seg * 8 + r8;
            load_lds16(Zb + (size_t)(row0 + m) * DMODEL + kt * 64 + cchunk * 8,
                       As + seg * 512);
        }
        #pragma unroll
        for (int j = 0; j < 2; ++j) {
            int seg = wid * 2 + j;
            int n = seg * 8 + r8;
            load_lds16(WoT + (size_t)(col0 + n) * DMODEL + kt * 64 + cchunk * 8,
                       Bs + seg * 512);
        }
        __syncthreads();

        #pragma unroll
        for (int ks = 0; ks < 2; ++ks) {
            const int c = ks * 4 + quad;
            short8 af[2], bf[4];
            #pragma unroll
            for (int mt = 0; mt < 2; ++mt) {
                int m = wid * 32 + mt * 16 + l16;
                af[mt] = *reinterpret_cast<const short8*>(As + m * 64 + ((c ^ (m & 7)) << 3));
            }
            #pragma unroll
            for (int nt = 0; nt < 4; ++nt) {
                int n = nt * 16 + l16;
                bf[nt] = *reinterpret_cast<const short8*>(Bs + n * 64 + ((c ^ (n & 7)) << 3));
            }
            #pragma unroll
            for (int mt = 0; mt < 2; ++mt)
                #pragma unroll
                for (int nt = 0; nt < 4; ++nt)
                    acc[mt][nt] = __builtin_amdgcn_mfma_f32_16x16x32_bf16(
                        af[mt], bf[nt], acc[mt][nt], 0, 0, 0);
        }
    }

    #pragma unroll
    for (int mt = 0; mt < 2; ++mt) {
        const int mmbase = row0 + wid * 32 + mt * 16 + quad * 4;
        #pragma unroll
        for (int nt = 0; nt < 4; ++nt) {
            const int nn = col0 + nt * 16 + l16;
            const float bias_v = bo[nn];
            #pragma unroll
            for (int r = 0; r < 4; ++r)
                out[(size_t)(mmbase + r) * DMODEL + nn] = acc[mt][nt][r] + bias_v;
        }
    }
}

// ---------------- flash attention: zero-LDS, software-pipelined main loop -------
__global__ __launch_bounds__(256) void attn_mfma(
    const __hip_bfloat16* __restrict__ Q2,
    const __hip_bfloat16* __restrict__ K2,
    const __hip_bfloat16* __restrict__ V2,
    __hip_bfloat16* __restrict__ Z)         // [B,L,512] bf16
{
    __shared__ float smem[4608];            // Lred [256] + Ored [4352] (stride 68)
    float* Lred = smem;
    float* Ored = smem + 256;

    const int bh = (blockIdx.x & 7) * 4 + ((blockIdx.x >> 3) & 3);
    const int qt = blockIdx.x >> 5;
    const int q0 = qt * 64;
    const int tid = threadIdx.x;
    const int wid = tid >> 6, lane = tid & 63;
    const int l16 = lane & 15, quad = lane >> 4;

    const __hip_bfloat16* Kc = K2 + (((size_t)bh * 128 * 2) << 9);
    const __hip_bfloat16* Vc = V2 + (((size_t)bh * 64 * 4) << 9);

    short8 qb[4][2];
    #pragma unroll
    for (int nt = 0; nt < 4; ++nt)
        #pragma unroll
        for (int s = 0; s < 2; ++s)
            qb[nt][s] = *reinterpret_cast<const short8*>(
                Q2 + ((((size_t)bh * 128 + qt * 4 + nt) * 2 + s) << 9) + lane * 8);

    floatx4 acc[4][4];
    #pragma unroll
    for (int i = 0; i < 4; ++i)
        #pragma unroll
        for (int j = 0; j < 4; ++j) acc[i][j] = floatx4{0.f, 0.f, 0.f, 0.f};
    float lsum[4] = {0.f, 0.f, 0.f, 0.f};

    const floatx4 fzero = floatx4{0.f, 0.f, 0.f, 0.f};

    const __hip_bfloat16* kp = Kc + (((size_t)wid * 4) << 9) + lane * 8;
    const __hip_bfloat16* vp = Vc + (((size_t)wid * 4) << 9) + lane * 8;

    // prologue: load tile 0, compute S_0
    short8 kb[2][2], vbuf[2][4];
    #pragma unroll
    for (int t = 0; t < 2; ++t)
        #pragma unroll
        for (int s = 0; s < 2; ++s)
            kb[t][s] = *reinterpret_cast<const short8*>(kp + ((t * 2 + s) << 9));
    #pragma unroll
    for (int dt = 0; dt < 4; ++dt)
        vbuf[0][dt] = *reinterpret_cast<const short8*>(vp + (dt << 9));
    kp += (size_t)16 << 9;
    vp += (size_t)16 << 9;

    floatx4 sacc[2][4];
    #pragma unroll
    for (int nt = 0; nt < 4; ++nt) {
        sacc[0][nt] = __builtin_amdgcn_mfma_f32_16x16x32_bf16(kb[0][0], qb[nt][0], fzero, 0, 0, 0);
        sacc[1][nt] = __builtin_amdgcn_mfma_f32_16x16x32_bf16(kb[1][0], qb[nt][0], fzero, 0, 0, 0);
    }
    #pragma unroll
    for (int nt = 0; nt < 4; ++nt) {
        sacc[0][nt] = __builtin_amdgcn_mfma_f32_16x16x32_bf16(kb[0][1], qb[nt][1], sacc[0][nt], 0, 0, 0);
        sacc[1][nt] = __builtin_amdgcn_mfma_f32_16x16x32_bf16(kb[1][1], qb[nt][1], sacc[1][nt], 0, 0, 0);
    }

    #pragma unroll
    for (int kt = 0; kt < 16; ++kt) {
        const int cur = kt & 1, nxt = cur ^ 1;

        // 1) issue loads for tile kt+1 (consumed by S below / PV next iter)
        if (kt < 15) {
            #pragma unroll
            for (int t = 0; t < 2; ++t)
                #pragma unroll
                for (int s = 0; s < 2; ++s)
                    kb[t][s] = *reinterpret_cast<const short8*>(kp + ((t * 2 + s) << 9));
            #pragma unroll
            for (int dt = 0; dt < 4; ++dt)
                vbuf[nxt][dt] = *reinterpret_cast<const short8*>(vp + (dt << 9));
            kp += (size_t)16 << 9;
            vp += (size_t)16 << 9;
        }

        // 2) softmax of tile kt (VALU) — overlaps the other wave's MFMA burst
        short8 pa[4];
        #pragma unroll
        for (int nt = 0; nt < 4; ++nt) {
            float e[8];
            #pragma unroll
            for (int t = 0; t < 2; ++t)
                #pragma unroll
                for (int r = 0; r < 4; ++r)
                    e[t * 4 + r] = fast_exp2(sacc[t][nt][r]);
            union { short8 s8; __hip_bfloat16 h[8]; } u;
            #pragma unroll
            for (int i = 0; i < 8; ++i) u.h[i] = __float2bfloat16(e[i]);
            lsum[nt] += ((e[0] + e[1]) + (e[2] + e[3])) + ((e[4] + e[5]) + (e[6] + e[7]));
            pa[nt] = u.s8;
        }

        // 3) S for tile kt+1 (MFMA, independent of pa) — contiguous MFMA burst
        if (kt < 15) {
            #pragma unroll
            for (int nt = 0; nt < 4; ++nt) {
                sacc[0][nt] = __builtin_amdgcn_mfma_f32_16x16x32_bf16(
                    kb[0][0], qb[nt][0], fzero, 0, 0, 0);
                sacc[1][nt] = __builtin_amdgcn_mfma_f32_16x16x32_bf16(
                    kb[1][0], qb[nt][0], fzero, 0, 0, 0);
            }
            #pragma unroll
            for (int nt = 0; nt < 4; ++nt) {
                sacc[0][nt] = __builtin_amdgcn_mfma_f32_16x16x32_bf16(
                    kb[0][1], qb[nt][1], sacc[0][nt], 0, 0, 0);
                sacc[1][nt] = __builtin_amdgcn_mfma_f32_16x16x32_bf16(
                    kb[1][1], qb[nt][1], sacc[1][nt], 0, 0, 0);
            }
        }

        // 4) PV for tile kt
        #pragma unroll
        for (int dt = 0; dt < 4; ++dt)
            #pragma unroll
            for (int nt = 0; nt < 4; ++nt)
                acc[nt][dt] = __builtin_amdgcn_mfma_f32_16x16x32_bf16(
                    pa[nt], vbuf[cur][dt], acc[nt][dt], 0, 0, 0);
    }

    // -------- epilogue: cross-wave reduction of lsum and O --------
    #pragma unroll
    for (int nt = 0; nt < 4; ++nt) {
        float v = lsum[nt];
        v += __shfl_xor(v, 16);
        v += __shfl_xor(v, 32);
        lsum[nt] = v;
    }
    if (quad == 0) {
        #pragma unroll
        for (int nt = 0; nt < 4; ++nt)
            Lred[wid * 64 + nt * 16 + l16] = lsum[nt];
    }

    const int b = bh >> 3, h = bh & 7;
    const int ql = tid >> 2;
    const int dg = tid & 3;
    float inv = 0.f;

    for (int dt = 0; dt < 4; ++dt) {
        __syncthreads();
        #pragma unroll
        for (int nt = 0; nt < 4; ++nt)
            *reinterpret_cast<floatx4*>(
                &Ored[(wid * 16 + l16) * 68 + nt * 16 + quad * 4]) = acc[nt][dt];
        __syncthreads();

        if (dt == 0)
            inv = 1.f / (Lred[ql] + Lred[64 + ql] + Lred[128 + ql] + Lred[192 + ql]);

        bf16x4 zo;
        #pragma unroll
        for (int i = 0; i < 4; ++i) {
            int d = dg * 4 + i;
            float ssum = Ored[d * 68 + ql] + Ored[(16 + d) * 68 + ql]
                       + Ored[(32 + d) * 68 + ql] + Ored[(48 + d) * 68 + ql];
            zo.v[i] = __float2bfloat16(ssum * inv);
        }
        *reinterpret_cast<bf16x4*>(
            Z + (size_t)(b * LSEQ + q0 + ql) * DMODEL + h * 64 + dt * 16 + dg * 4) = zo;
    }
}

extern "C" void kernel_launch(void* const* d_in, const int* in_sizes, int n_in,
                              void* d_out, int out_size, void* d_ws, size_t ws_size,
                              hipStream_t stream)
{
    const float* x  = (const float*)d_in[0];
    const float* Wq = (const float*)d_in[1]; const float* bq = (const float*)d_in[2];
    const float* Wk = (const float*)d_in[3]; const float* bk = (const float*)d_in[4];
    const float* Wv = (const float*)d_in[5]; const float* bv = (const float*)d_in[6];
    const float* Wo = (const float*)d_in[7]; const float* bo = (const float*)d_in[8];
    float* out = (float*)d_out;

    const size_t nqkv = (size_t)MDIM * DMODEL;
    __hip_bfloat16* xb = (__hip_bfloat16*)d_ws;
    __hip_bfloat16* Wt = xb + nqkv;
    __hip_bfloat16* Q2 = Wt + ((size_t)4 << 18);
    __hip_bfloat16* K2 = Q2 + nqkv;
    __hip_bfloat16* V2 = K2 + nqkv;
    __hip_bfloat16* Zb = V2 + nqkv;

    cast_x_kernel<<<dim3(MDIM * DMODEL / (256 * 8)), 256, 0, stream>>>(x, xb);
    transpose_cast_w<<<dim3(16, 16, 4), 256, 0, stream>>>(Wq, Wk, Wv, Wo, Wt);

    gemm_qkv_mfma<<<dim3(MDIM / 128, 12), 256, 0, stream>>>(
        xb, Wt, bq, bk, bv, Q2, K2, V2);

    attn_mfma<<<dim3(32 * (LSEQ / 64)), 256, 0, stream>>>(Q2, K2, V2, Zb);

    gemm_out_mfma<<<dim3(MDIM / 128, DMODEL / 64), 256, 0, stream>>>(
        Zb, Wt + ((size_t)3 << 18), bo, out);
}